// Round 3
// baseline (2042.269 us; speedup 1.0000x reference)
//
#include <hip/hip_runtime.h>
#include <cstdint>
#include <cstddef>

typedef uint16_t u16;
typedef __attribute__((ext_vector_type(8))) short bf16x8;   // 8 bf16 = 4 VGPRs (guide §3)
typedef __attribute__((ext_vector_type(4))) float f32x4;
typedef __attribute__((ext_vector_type(4))) uint16_t u16x4;

#define GLOBAL_AS(p) (const __attribute__((address_space(1))) void*)(p)
#define LDS_AS(p)    (__attribute__((address_space(3))) void*)(p)

// raw-barrier sync points (avoid __syncthreads' forced vmcnt(0) drain; guide §5 T3/T4)
__device__ __forceinline__ void wait_all_bar(){
  asm volatile("s_waitcnt vmcnt(0) lgkmcnt(0)" ::: "memory");
  __builtin_amdgcn_s_barrier();
  asm volatile("" ::: "memory");
}
__device__ __forceinline__ void wait_lgkm_bar(){   // LDS-only sync; leaves global loads in flight
  asm volatile("s_waitcnt lgkmcnt(0)" ::: "memory");
  __builtin_amdgcn_s_barrier();
  asm volatile("" ::: "memory");
}

__device__ __forceinline__ u16 f2b(float f){
  uint32_t u = __float_as_uint(f);
  u += 0x7fff + ((u >> 16) & 1);            // RNE
  return (u16)(u >> 16);
}
__device__ __forceinline__ float b2f(u16 h){
  return __uint_as_float(((uint32_t)h) << 16);
}

// ---------------- fp32 -> bf16 convert (vector x4) ----------------
__global__ void cvt_bf16_kernel(const float* __restrict__ src, u16* __restrict__ dst, int n){
  int i = (blockIdx.x * 256 + threadIdx.x) * 4;
  if (i >= n) return;
  float4 f = *(const float4*)(src + i);
  u16x4 o; o.x = f2b(f.x); o.y = f2b(f.y); o.z = f2b(f.z); o.w = f2b(f.w);
  *(u16x4*)(dst + i) = o;
}

// ------- fused fp32->bf16 convert + copy + transpose (block-1 input path) -------
__global__ void cvtT_kernel(const float* __restrict__ src, u16* __restrict__ x, u16* __restrict__ xT){
  __shared__ u16 tile[64][68];
  size_t b = blockIdx.y;
  int t = blockIdx.x;
  int r0 = (t >> 3) * 64, c0 = (t & 7) * 64;
  const float* s = src + b * 262144;
  u16* dx = x + b * 262144;
  u16* dT = xT + b * 262144;
  int tx = threadIdx.x & 63, ty = threadIdx.x >> 6;
  #pragma unroll
  for (int k = 0; k < 16; k++){
    int r = ty * 16 + k;
    u16 v = f2b(s[(size_t)(r0 + r) * 512 + c0 + tx]);
    dx[(size_t)(r0 + r) * 512 + c0 + tx] = v;
    tile[r][tx] = v;
  }
  __syncthreads();
  #pragma unroll
  for (int k = 0; k < 16; k++){
    int c = ty * 16 + k;
    dT[(size_t)(c0 + c) * 512 + r0 + tx] = tile[tx][c];
  }
}

// ---------------- 512x512 bf16 transpose (batched, 64x64 tiles) ----------------
__global__ void transpose512_kernel(const u16* __restrict__ src, u16* __restrict__ dst){
  __shared__ u16 tile[64][68];
  size_t b = blockIdx.y;
  int t = blockIdx.x;
  int r0 = (t >> 3) * 64, c0 = (t & 7) * 64;
  const u16* s = src + b * 262144;
  u16* d = dst + b * 262144;
  int tx = threadIdx.x & 63, ty = threadIdx.x >> 6;
  #pragma unroll
  for (int k = 0; k < 16; k++){
    int r = ty * 16 + k;
    tile[r][tx] = s[(size_t)(r0 + r) * 512 + c0 + tx];
  }
  __syncthreads();
  #pragma unroll
  for (int k = 0; k < 16; k++){
    int c = ty * 16 + k;
    d[(size_t)(c0 + c) * 512 + r0 + tx] = tile[tx][c];
  }
}

// ======== fused attention: S = q@x^T, P = softmax(S), mix = P@x  (per batch) ========
// v3: barrier-free k-loops. B-operand fragments (x rows / xT rows) are loaded
// GLOBAL->REGISTER directly (per-lane addresses ARE the MFMA B fragment layout);
// x/xT are L2-resident per XCD, so no LDS staging and NO barriers in the k-loops.
// QBLK=32 rows/block, 8 waves (wave w owns keys [w*64,w*64+64)); LDS = U(q,P) only
// (~35 KB) and VGPR<=128 via launch_bounds(512,4) -> 2 blocks/CU co-resident.
__global__ __launch_bounds__(512, 4) void attn_kernel(
    const u16* __restrict__ q, const u16* __restrict__ x, const u16* __restrict__ xT,
    u16* __restrict__ mix, int batPerXcd)
{
  __shared__ __align__(16) u16 U[32 * 520];     // 33.3 KB: q-tile, then P (bf16)
  __shared__ float stats[2][32][8];             // row max / row sum partials per wave
  const int64_t E = 262144;
  int id = blockIdx.x;
  int tile = (id >> 3) & 15;
  int64_t bat = (int64_t)(id & 7) * batPerXcd + (id >> 7);
  q += bat * E; x += bat * E; xT += bat * E; mix += bat * E;
  int m0 = tile * 32;
  int tid = threadIdx.x, lane = tid & 63, w = tid >> 6;
  int fr = lane & 15, qd = lane >> 4, fq = qd * 8;

  // q-tile [32x512] -> U pitch 520 via global_load_lds (dest = uniform base + lane*16: legal).
  // wave w, chunk c stages full row c*8+w.
  #pragma unroll
  for (int c = 0; c < 4; c++){
    int row = c * 8 + w;
    __builtin_amdgcn_global_load_lds(GLOBAL_AS(q + (size_t)(m0 + row) * 512 + lane * 8),
                                     LDS_AS(&U[row * 520 + lane * 8]), 16, 0, 0);
  }
  wait_all_bar();                               // q-tile visible; only barrier before softmax

  // per-lane element offsets of this lane's B-fragment rows (shared by phase 1 and 3)
  int vo[4];
  #pragma unroll
  for (int j = 0; j < 4; j++) vo[j] = (w * 64 + j * 16 + fr) * 512 + fq;

  f32x4 acc[2][4];
  #pragma unroll
  for (int i = 0; i < 2; i++)
    #pragma unroll
    for (int j = 0; j < 4; j++) acc[i][j] = (f32x4){0.f, 0.f, 0.f, 0.f};

  // ---- phase 1: S = q @ x^T ; B fragments stream global->reg, 1-deep prefetch ----
  bf16x8 cur[4], nxt[4];
  #pragma unroll
  for (int j = 0; j < 4; j++) cur[j] = *(const bf16x8*)(x + vo[j]);
  #pragma unroll
  for (int it = 0; it < 16; ++it){
    #pragma unroll
    for (int j = 0; j < 4; j++)
      if (it < 15) nxt[j] = *(const bf16x8*)(x + vo[j] + (it + 1) * 32);
    int k0 = it * 32;
    bf16x8 a0 = *(const bf16x8*)&U[fr * 520 + k0 + fq];
    bf16x8 a1 = *(const bf16x8*)&U[(16 + fr) * 520 + k0 + fq];
    #pragma unroll
    for (int j = 0; j < 4; j++){
      acc[0][j] = __builtin_amdgcn_mfma_f32_16x16x32_bf16(a0, cur[j], acc[0][j], 0, 0, 0);
      acc[1][j] = __builtin_amdgcn_mfma_f32_16x16x32_bf16(a1, cur[j], acc[1][j], 0, 0, 0);
    }
    #pragma unroll
    for (int j = 0; j < 4; j++) cur[j] = nxt[j];
  }

  // prefetch phase-3 first fragments (xT) now; they fly under the whole softmax
  #pragma unroll
  for (int j = 0; j < 4; j++) cur[j] = *(const bf16x8*)(xT + vo[j]);

  // ---- phase 2: softmax over full 512 keys ----
  // S C-layout: row(l) = i*16 + qd*4 + r, col(key) = w*64 + j*16 + fr
  float inv[2][4];
  #pragma unroll
  for (int i = 0; i < 2; i++)
    #pragma unroll
    for (int r = 0; r < 4; r++){
      float m = acc[i][0][r];
      #pragma unroll
      for (int j = 1; j < 4; j++) m = fmaxf(m, acc[i][j][r]);
      #pragma unroll
      for (int o = 1; o <= 8; o <<= 1) m = fmaxf(m, __shfl_xor(m, o));
      if (fr == 0) stats[0][i * 16 + qd * 4 + r][w] = m;
    }
  wait_lgkm_bar();    // LDS-only sync: xT prefetch stays in flight
  #pragma unroll
  for (int i = 0; i < 2; i++)
    #pragma unroll
    for (int r = 0; r < 4; r++){
      int row = i * 16 + qd * 4 + r;
      float m = stats[0][row][0];
      #pragma unroll
      for (int t = 1; t < 8; t++) m = fmaxf(m, stats[0][row][t]);
      float s = 0.f;
      #pragma unroll
      for (int j = 0; j < 4; j++){
        float e = __expf(acc[i][j][r] - m);
        acc[i][j][r] = e; s += e;
      }
      #pragma unroll
      for (int o = 1; o <= 8; o <<= 1) s += __shfl_xor(s, o);
      if (fr == 0) stats[1][row][w] = s;
    }
  wait_lgkm_bar();
  #pragma unroll
  for (int i = 0; i < 2; i++)
    #pragma unroll
    for (int r = 0; r < 4; r++){
      int row = i * 16 + qd * 4 + r;
      float s = stats[1][row][0];
      #pragma unroll
      for (int t = 1; t < 8; t++) s += stats[1][row][t];
      inv[i][r] = 1.0f / s;
    }
  // P (bf16) -> U, pair-packed b32 (even lane writes its + neighbor's col)
  #pragma unroll
  for (int i = 0; i < 2; i++)
    #pragma unroll
    for (int r = 0; r < 4; r++)
      #pragma unroll
      for (int j = 0; j < 4; j++){
        int row = i * 16 + qd * 4 + r;
        int col = w * 64 + j * 16 + fr;
        uint32_t mine = f2b(acc[i][j][r] * inv[i][r]);
        uint32_t oth = (uint32_t)__shfl_xor((int)mine, 1);
        if (!(fr & 1)) *(uint32_t*)&U[row * 520 + col] = mine | (oth << 16);
      }
  wait_lgkm_bar();    // P visible to all waves; xT loads still in flight

  // ---- phase 3: mix = P @ x ; identical barrier-free stream on xT ----
  #pragma unroll
  for (int i = 0; i < 2; i++)
    #pragma unroll
    for (int j = 0; j < 4; j++) acc[i][j] = (f32x4){0.f, 0.f, 0.f, 0.f};
  #pragma unroll
  for (int it = 0; it < 16; ++it){
    #pragma unroll
    for (int j = 0; j < 4; j++)
      if (it < 15) nxt[j] = *(const bf16x8*)(xT + vo[j] + (it + 1) * 32);
    int k0 = it * 32;
    bf16x8 a0 = *(const bf16x8*)&U[fr * 520 + k0 + fq];
    bf16x8 a1 = *(const bf16x8*)&U[(16 + fr) * 520 + k0 + fq];
    #pragma unroll
    for (int j = 0; j < 4; j++){
      acc[0][j] = __builtin_amdgcn_mfma_f32_16x16x32_bf16(a0, cur[j], acc[0][j], 0, 0, 0);
      acc[1][j] = __builtin_amdgcn_mfma_f32_16x16x32_bf16(a1, cur[j], acc[1][j], 0, 0, 0);
    }
    #pragma unroll
    for (int j = 0; j < 4; j++) cur[j] = nxt[j];
  }
  // epilogue: mix bf16, C-layout
  #pragma unroll
  for (int i = 0; i < 2; i++)
    #pragma unroll
    for (int j = 0; j < 4; j++)
      #pragma unroll
      for (int r = 0; r < 4; r++)
        mix[(size_t)(m0 + i * 16 + qd * 4 + r) * 512 + w * 64 + j * 16 + fr] =
            f2b(acc[i][j][r]);
}

// ---------------- bf16 MFMA GEMM: C[512,512] = A[512,K] @ B[512,K]^T (batched) ----------------
// XCD swizzle: m0 = bx&3 so same-XCD blocks (bx, bx+8) share the A m-tile (L2 reuse).
// Min-2-phase pipelined staging (double-buffered As/Bs, raw barriers).
template<bool SPLIT, bool TANH, bool POOL, typename CT>
__global__ __launch_bounds__(256, 2) void gemm_bt_kernel(
    const u16* __restrict__ A0, const u16* __restrict__ A1,
    const u16* __restrict__ B, CT* __restrict__ C,
    int K, int ldb, int64_t aBatch, int64_t bBatch, int64_t cBatch,
    float* __restrict__ poolOut, int b0)
{
  __shared__ __align__(16) u16 As[2][128 * 32];
  __shared__ __align__(16) u16 Bs[2][128 * 32];
  int64_t bat = blockIdx.y;
  int m0 = (blockIdx.x & 3) * 128, n0 = (blockIdx.x >> 2) * 128;
  A0 += bat * aBatch;
  if (SPLIT) A1 += bat * aBatch;
  B += bat * bBatch;
  if (!POOL) C += bat * cBatch;
  int tid = threadIdx.x, lane = tid & 63;
  int w = tid >> 6;
  int wm = (w >> 1) * 64, wn = (w & 1) * 64;
  f32x4 acc[4][4];
  #pragma unroll
  for (int i = 0; i < 4; i++)
    #pragma unroll
    for (int j = 0; j < 4; j++) acc[i][j] = (f32x4){0.f, 0.f, 0.f, 0.f};

  int sRow = tid >> 2, sCol = (tid & 3) * 8;
  int fr = lane & 15, fq = (lane >> 4) * 8;

  auto stageG = [&](int buf, int k0){
    const u16* Ap = A0; int kk = k0;
    if (SPLIT && k0 >= 512){ Ap = A1; kk = k0 - 512; }
    const u16* ga = Ap + (size_t)(m0 + sRow) * 512 + kk + sCol;
    const u16* gb = B  + (size_t)(n0 + sRow) * ldb + k0 + sCol;
    __builtin_amdgcn_global_load_lds(GLOBAL_AS(ga),                    LDS_AS(&As[buf][tid * 8]),        16, 0, 0);
    __builtin_amdgcn_global_load_lds(GLOBAL_AS(ga + (size_t)64 * 512), LDS_AS(&As[buf][2048 + tid * 8]), 16, 0, 0);
    __builtin_amdgcn_global_load_lds(GLOBAL_AS(gb),                    LDS_AS(&Bs[buf][tid * 8]),        16, 0, 0);
    __builtin_amdgcn_global_load_lds(GLOBAL_AS(gb + (size_t)64 * ldb), LDS_AS(&Bs[buf][2048 + tid * 8]), 16, 0, 0);
  };

  stageG(0, 0);
  wait_all_bar();

  int nIt = K >> 5;
  for (int it = 0; it < nIt; ++it){
    if (it + 1 < nIt) stageG((it + 1) & 1, (it + 1) * 32);
    bf16x8 af[4], bfr[4];
    #pragma unroll
    for (int i = 0; i < 4; i++) af[i]  = *(const bf16x8*)&As[it & 1][(wm + i * 16 + fr) * 32 + fq];
    #pragma unroll
    for (int j = 0; j < 4; j++) bfr[j] = *(const bf16x8*)&Bs[it & 1][(wn + j * 16 + fr) * 32 + fq];
    #pragma unroll
    for (int i = 0; i < 4; i++)
      #pragma unroll
      for (int j = 0; j < 4; j++)
        acc[i][j] = __builtin_amdgcn_mfma_f32_16x16x32_bf16(af[i], bfr[j], acc[i][j], 0, 0, 0);
    wait_all_bar();
  }

  if constexpr (POOL){
    #pragma unroll
    for (int j = 0; j < 4; j++){
      float p = 0.f;
      #pragma unroll
      for (int i = 0; i < 4; i++)
        #pragma unroll
        for (int r = 0; r < 4; r++) p += acc[i][j][r];
      p += __shfl_xor(p, 16);
      p += __shfl_xor(p, 32);
      if (lane < 16){
        int col = n0 + wn + j * 16 + lane;
        atomicAdd(poolOut + ((size_t)(b0) + bat) * 512 + col, p * (1.0f / 512.0f));
      }
    }
  } else {
    int cq = (lane >> 4) * 4, cc = lane & 15;
    #pragma unroll
    for (int i = 0; i < 4; i++){
      #pragma unroll
      for (int j = 0; j < 4; j++){
        #pragma unroll
        for (int r = 0; r < 4; r++){
          int row = m0 + wm + i * 16 + cq + r;
          int col = n0 + wn + j * 16 + cc;
          float v = acc[i][j][r];
          if (TANH) v = tanhf(v);
          if constexpr (sizeof(CT) == 4) C[(size_t)row * 512 + col] = v;
          else                           C[(size_t)row * 512 + col] = f2b(v);
        }
      }
    }
  }
}

extern "C" void kernel_launch(void* const* d_in, const int* in_sizes, int n_in,
                              void* d_out, int out_size, void* d_ws, size_t ws_size,
                              hipStream_t stream) {
  const float* emb   = (const float*)d_in[0];   // [256,512,512]
  const float* Win1  = (const float*)d_in[1];   // [512,512]
  const float* Wout1 = (const float*)d_in[2];   // [512,1024]
  const float* Win2  = (const float*)d_in[3];
  const float* Wout2 = (const float*)d_in[4];
  float* out = (float*)d_out;                   // [256,512]

  // workspace: 4 MB weights + CB * 5 bf16 buffers (x, q, xT, xNext, mix)
  int CB = 256;
  while (CB > 8 && (4ull << 20) + (size_t)CB * (5ull * 524288ull) > ws_size) CB >>= 1;
  const int64_t E = 262144;

  char* wsb = (char*)d_ws;
  u16* Win1b  = (u16*)wsb;
  u16* Wout1b = Win1b + 262144;
  u16* Win2b  = Wout1b + 524288;
  u16* Wout2b = Win2b + 262144;
  u16* base = (u16*)(wsb + (4 << 20));
  // live ranges: Ar: x1 -> q2 | Br: q1 | Cr: xT1 -> xT2 | Dr: x2 | Fr: mix1 -> mix2
  u16* Ar = base;
  u16* Br = base + (size_t)CB * E;
  u16* Cr = base + 2 * (size_t)CB * E;
  u16* Dr = base + 3 * (size_t)CB * E;
  u16* Fr = base + 4 * (size_t)CB * E;

  hipMemsetAsync(d_out, 0, (size_t)out_size * sizeof(float), stream);

  cvt_bf16_kernel<<<256, 256, 0, stream>>>(Win1,  Win1b,  262144);
  cvt_bf16_kernel<<<512, 256, 0, stream>>>(Wout1, Wout1b, 524288);
  cvt_bf16_kernel<<<256, 256, 0, stream>>>(Win2,  Win2b,  262144);
  cvt_bf16_kernel<<<512, 256, 0, stream>>>(Wout2, Wout2b, 524288);

  dim3 gg(16, CB);        // gemm grid
  dim3 gt(64, CB);        // transpose / cvtT tiles
  int nAttnBlocks = CB * 16;   // QBLK=32 -> 16 q-tiles per batch
  int batPerXcd = CB / 8;

  for (int c = 0; c < 256 / CB; c++){
    const float* embc = emb + (size_t)c * CB * 262144;
    int b0 = c * CB;

    // ---- block 1 (tanh) ----
    cvtT_kernel<<<gt, 256, 0, stream>>>(embc, Ar, Cr);                     // x1 -> Ar, xT1 -> Cr
    gemm_bt_kernel<false,false,false,u16><<<gg, 256, 0, stream>>>(
        Ar, nullptr, Win1b, Br, 512, 512, E, 0, E, nullptr, 0);            // q1 -> Br
    attn_kernel<<<nAttnBlocks, 512, 0, stream>>>(Br, Ar, Cr, Fr, batPerXcd); // mix1 -> Fr
    gemm_bt_kernel<true,true,false,u16><<<gg, 256, 0, stream>>>(
        Fr, Br, Wout1b, Dr, 1024, 1024, E, 0, E, nullptr, 0);              // x2 -> Dr (tanh)

    // ---- block 2 (no tanh) + fused mean-pool ----
    transpose512_kernel<<<gt, 256, 0, stream>>>(Dr, Cr);                   // xT2 -> Cr
    gemm_bt_kernel<false,false,false,u16><<<gg, 256, 0, stream>>>(
        Dr, nullptr, Win2b, Ar, 512, 512, E, 0, E, nullptr, 0);            // q2 -> Ar
    attn_kernel<<<nAttnBlocks, 512, 0, stream>>>(Ar, Dr, Cr, Fr, batPerXcd); // mix2 -> Fr
    gemm_bt_kernel<true,false,true,u16><<<gg, 256, 0, stream>>>(
        Fr, Ar, Wout2b, (u16*)nullptr, 1024, 1024, E, 0, 0, out, b0);      // pooled out
  }
}

// Round 4
// 1709.039 us; speedup vs baseline: 1.1950x; 1.1950x over previous
//
#include <hip/hip_runtime.h>
#include <cstdint>
#include <cstddef>

typedef uint16_t u16;
typedef __attribute__((ext_vector_type(8))) short bf16x8;   // 8 bf16 = 4 VGPRs (guide §3)
typedef __attribute__((ext_vector_type(4))) float f32x4;
typedef __attribute__((ext_vector_type(4))) uint16_t u16x4;

#define GLOBAL_AS(p) (const __attribute__((address_space(1))) void*)(p)
#define LDS_AS(p)    (__attribute__((address_space(3))) void*)(p)

// T4 counted-vmcnt barriers: prefetch loads stay in flight across barriers.
__device__ __forceinline__ void bar_vm4(){      // wait until <=4 vmem outstanding
  asm volatile("s_waitcnt vmcnt(4)" ::: "memory");
  __builtin_amdgcn_s_barrier();
  asm volatile("" ::: "memory");
}
__device__ __forceinline__ void bar_vm0(){      // full drain (loop tail only)
  asm volatile("s_waitcnt vmcnt(0)" ::: "memory");
  __builtin_amdgcn_s_barrier();
  asm volatile("" ::: "memory");
}
__device__ __forceinline__ void bar_end(){      // execution-only barrier (reads already consumed)
  asm volatile("" ::: "memory");
  __builtin_amdgcn_s_barrier();
  asm volatile("" ::: "memory");
}
__device__ __forceinline__ void bar_lgkm(){     // LDS-only sync; vmem prefetch stays in flight
  asm volatile("s_waitcnt lgkmcnt(0)" ::: "memory");
  __builtin_amdgcn_s_barrier();
  asm volatile("" ::: "memory");
}

__device__ __forceinline__ u16 f2b(float f){
  uint32_t u = __float_as_uint(f);
  u += 0x7fff + ((u >> 16) & 1);            // RNE
  return (u16)(u >> 16);
}

// ---------------- fp32 -> bf16 convert (vector x4) ----------------
__global__ void cvt_bf16_kernel(const float* __restrict__ src, u16* __restrict__ dst, int n){
  int i = (blockIdx.x * 256 + threadIdx.x) * 4;
  if (i >= n) return;
  float4 f = *(const float4*)(src + i);
  u16x4 o; o.x = f2b(f.x); o.y = f2b(f.y); o.z = f2b(f.z); o.w = f2b(f.w);
  *(u16x4*)(dst + i) = o;
}

// ------- fused fp32->bf16 convert + copy + transpose (block-1 input path) -------
__global__ void cvtT_kernel(const float* __restrict__ src, u16* __restrict__ x, u16* __restrict__ xT){
  __shared__ u16 tile[64][68];
  size_t b = blockIdx.y;
  int t = blockIdx.x;
  int r0 = (t >> 3) * 64, c0 = (t & 7) * 64;
  const float* s = src + b * 262144;
  u16* dx = x + b * 262144;
  u16* dT = xT + b * 262144;
  int tx = threadIdx.x & 63, ty = threadIdx.x >> 6;
  #pragma unroll
  for (int k = 0; k < 16; k++){
    int r = ty * 16 + k;
    u16 v = f2b(s[(size_t)(r0 + r) * 512 + c0 + tx]);
    dx[(size_t)(r0 + r) * 512 + c0 + tx] = v;
    tile[r][tx] = v;
  }
  __syncthreads();
  #pragma unroll
  for (int k = 0; k < 16; k++){
    int c = ty * 16 + k;
    dT[(size_t)(c0 + c) * 512 + r0 + tx] = tile[tx][c];
  }
}

// ---------------- 512x512 bf16 transpose (batched, 64x64 tiles) ----------------
__global__ void transpose512_kernel(const u16* __restrict__ src, u16* __restrict__ dst){
  __shared__ u16 tile[64][68];
  size_t b = blockIdx.y;
  int t = blockIdx.x;
  int r0 = (t >> 3) * 64, c0 = (t & 7) * 64;
  const u16* s = src + b * 262144;
  u16* d = dst + b * 262144;
  int tx = threadIdx.x & 63, ty = threadIdx.x >> 6;
  #pragma unroll
  for (int k = 0; k < 16; k++){
    int r = ty * 16 + k;
    tile[r][tx] = s[(size_t)(r0 + r) * 512 + c0 + tx];
  }
  __syncthreads();
  #pragma unroll
  for (int k = 0; k < 16; k++){
    int c = ty * 16 + k;
    d[(size_t)(c0 + c) * 512 + r0 + tx] = tile[tx][c];
  }
}

// ======== fused attention: S = q@x^T, P = softmax(S), mix = P@x  (per batch) ========
// v4 = R1 structure + T4 counted vmcnt + T2 chunk swizzle.
// Per iter: stage(next tile, 4 loads) -> vmcnt(4) [prev tile done, next in flight]
// -> barrier -> ds_read+MFMA -> execution barrier. Prefetch is never drained.
// LDS rows are 64B (32 elems); chunk c of row r stored at slot c^((r>>1)&3), achieved by
// pre-swizzling the GLOBAL source chunk (linear global_load_lds dest, rule m104/m173);
// reads use the same XOR -> 2 lanes/bank (minimum for b128), was 8-way serialized.
__global__ __launch_bounds__(512, 2) void attn_kernel(
    const u16* __restrict__ q, const u16* __restrict__ x, const u16* __restrict__ xT,
    u16* __restrict__ mix, int batPerXcd)
{
  __shared__ __align__(16) u16 U[64 * 520];     // 66.6 KB: q-tile, then P (bf16)
  __shared__ __align__(16) u16 Bx[2][512 * 32]; // 2 x 32 KB double buffer
  __shared__ float stats[2][64][8];             // row max / row sum partials per wave
  const int64_t E = 262144;
  int id = blockIdx.x;
  int tile = (id >> 3) & 7;
  int64_t bat = (int64_t)(id & 7) * batPerXcd + (id >> 6);
  q += bat * E; x += bat * E; xT += bat * E; mix += bat * E;
  int m0 = tile * 64;
  int tid = threadIdx.x, lane = tid & 63, w = tid >> 6;
  int fr = lane & 15, qd = lane >> 4;
  int fq = qd * 8;                                    // U chunk (unswizzled; pitch 520 is ~2-way already)
  int sw = ((tid & 3) ^ ((tid >> 3) & 3)) * 8;        // swizzled source chunk for staging
  int bslot = (qd ^ ((fr >> 1) & 3)) * 8;             // swizzled read slot for Bx

  auto stage = [&](const u16* __restrict__ src, int buf, int k0){
    #pragma unroll
    for (int s = 0; s < 4; s++){
      const u16* g = src + (size_t)(s * 128 + (tid >> 2)) * 512 + k0 + sw;
      __builtin_amdgcn_global_load_lds(GLOBAL_AS(g), LDS_AS(&Bx[buf][s * 4096 + tid * 8]), 16, 0, 0);
    }
  };

  stage(x, 0, 0);                               // tile0 -> buf0

  // q-tile [64x512] -> U pitch 520 via global_load_lds (dest = uniform row base + lane*16).
  #pragma unroll
  for (int c = 0; c < 8; c++){
    int row = c * 8 + w;
    __builtin_amdgcn_global_load_lds(GLOBAL_AS(q + (size_t)(m0 + row) * 512 + lane * 8),
                                     LDS_AS(&U[row * 520 + lane * 8]), 16, 0, 0);
  }

  f32x4 acc[4][4];
  #pragma unroll
  for (int i = 0; i < 4; i++)
    #pragma unroll
    for (int j = 0; j < 4; j++) acc[i][j] = (f32x4){0.f, 0.f, 0.f, 0.f};

  // ---- phase 1: S = q @ x^T  (B^T-form input is x row-major) ----
  for (int it = 0; it < 16; ++it){
    if (it < 15) stage(x, (it + 1) & 1, (it + 1) * 32);
    else         stage(xT, 0, 0);     // phase-3 tile0; buf0 last read at it=14
    bar_vm4();                        // current tile (and q-tile at it=0) landed; prefetch in flight
    int k0 = it * 32;
    bf16x8 af[4], bfr[4];
    #pragma unroll
    for (int i = 0; i < 4; i++) af[i]  = *(const bf16x8*)&U[(i * 16 + fr) * 520 + k0 + fq];
    #pragma unroll
    for (int j = 0; j < 4; j++) bfr[j] = *(const bf16x8*)&Bx[it & 1][(w * 64 + j * 16 + fr) * 32 + bslot];
    #pragma unroll
    for (int i = 0; i < 4; i++)
      #pragma unroll
      for (int j = 0; j < 4; j++)
        acc[i][j] = __builtin_amdgcn_mfma_f32_16x16x32_bf16(af[i], bfr[j], acc[i][j], 0, 0, 0);
    bar_end();                        // reads consumed; next iter may overwrite other buffer
  }

  // ---- phase 2: softmax over full 512 keys (xT tile0 loads in flight throughout) ----
  // S C-layout: row(l) = i*16 + qd*4 + r, col(key) = w*64 + j*16 + fr
  float inv[4][4];
  #pragma unroll
  for (int i = 0; i < 4; i++)
    #pragma unroll
    for (int r = 0; r < 4; r++){
      float m = acc[i][0][r];
      #pragma unroll
      for (int j = 1; j < 4; j++) m = fmaxf(m, acc[i][j][r]);
      #pragma unroll
      for (int o = 1; o <= 8; o <<= 1) m = fmaxf(m, __shfl_xor(m, o));
      if (fr == 0) stats[0][i * 16 + qd * 4 + r][w] = m;
    }
  bar_lgkm();
  #pragma unroll
  for (int i = 0; i < 4; i++)
    #pragma unroll
    for (int r = 0; r < 4; r++){
      int row = i * 16 + qd * 4 + r;
      float m = stats[0][row][0];
      #pragma unroll
      for (int t = 1; t < 8; t++) m = fmaxf(m, stats[0][row][t]);
      float s = 0.f;
      #pragma unroll
      for (int j = 0; j < 4; j++){
        float e = __expf(acc[i][j][r] - m);
        acc[i][j][r] = e; s += e;
      }
      #pragma unroll
      for (int o = 1; o <= 8; o <<= 1) s += __shfl_xor(s, o);
      if (fr == 0) stats[1][row][w] = s;
    }
  bar_lgkm();
  #pragma unroll
  for (int i = 0; i < 4; i++)
    #pragma unroll
    for (int r = 0; r < 4; r++){
      int row = i * 16 + qd * 4 + r;
      float s = stats[1][row][0];
      #pragma unroll
      for (int t = 1; t < 8; t++) s += stats[1][row][t];
      inv[i][r] = 1.0f / s;
    }
  // P (bf16) -> U, pair-packed b32 (even lane writes its + neighbor's col)
  #pragma unroll
  for (int i = 0; i < 4; i++)
    #pragma unroll
    for (int r = 0; r < 4; r++)
      #pragma unroll
      for (int j = 0; j < 4; j++){
        int row = i * 16 + qd * 4 + r;
        int col = w * 64 + j * 16 + fr;
        uint32_t mine = f2b(acc[i][j][r] * inv[i][r]);
        uint32_t oth = (uint32_t)__shfl_xor((int)mine, 1);
        if (!(fr & 1)) *(uint32_t*)&U[row * 520 + col] = mine | (oth << 16);
      }
  bar_lgkm();         // P visible to all waves; xT tile0 still in flight (vmcnt untouched)

  // ---- phase 3: mix = P @ x  (B^T-form input is xT row-major) ----
  #pragma unroll
  for (int i = 0; i < 4; i++)
    #pragma unroll
    for (int j = 0; j < 4; j++) acc[i][j] = (f32x4){0.f, 0.f, 0.f, 0.f};
  for (int it = 0; it < 16; ++it){
    if (it < 15){ stage(xT, (it + 1) & 1, (it + 1) * 32); bar_vm4(); }
    else        { bar_vm0(); }
    int k0 = it * 32;
    bf16x8 af[4], bfr[4];
    #pragma unroll
    for (int i = 0; i < 4; i++) af[i]  = *(const bf16x8*)&U[(i * 16 + fr) * 520 + k0 + fq];
    #pragma unroll
    for (int j = 0; j < 4; j++) bfr[j] = *(const bf16x8*)&Bx[it & 1][(w * 64 + j * 16 + fr) * 32 + bslot];
    #pragma unroll
    for (int i = 0; i < 4; i++)
      #pragma unroll
      for (int j = 0; j < 4; j++)
        acc[i][j] = __builtin_amdgcn_mfma_f32_16x16x32_bf16(af[i], bfr[j], acc[i][j], 0, 0, 0);
    bar_end();
  }
  // epilogue: mix bf16, C-layout
  #pragma unroll
  for (int i = 0; i < 4; i++)
    #pragma unroll
    for (int j = 0; j < 4; j++)
      #pragma unroll
      for (int r = 0; r < 4; r++)
        mix[(size_t)(m0 + i * 16 + qd * 4 + r) * 512 + w * 64 + j * 16 + fr] =
            f2b(acc[i][j][r]);
}

// ---------------- bf16 MFMA GEMM: C[512,512] = A[512,K] @ B[512,K]^T (batched) ----------------
// XCD swizzle: m0 = bx&3 so same-XCD blocks (bx, bx+8) share the A m-tile (L2 reuse).
// Same T4 counted-vmcnt pipeline + T2 chunk swizzle as attn_kernel.
template<bool SPLIT, bool TANH, bool POOL, typename CT>
__global__ __launch_bounds__(256, 2) void gemm_bt_kernel(
    const u16* __restrict__ A0, const u16* __restrict__ A1,
    const u16* __restrict__ B, CT* __restrict__ C,
    int K, int ldb, int64_t aBatch, int64_t bBatch, int64_t cBatch,
    float* __restrict__ poolOut, int b0)
{
  __shared__ __align__(16) u16 As[2][128 * 32];
  __shared__ __align__(16) u16 Bs[2][128 * 32];
  int64_t bat = blockIdx.y;
  int m0 = (blockIdx.x & 3) * 128, n0 = (blockIdx.x >> 2) * 128;
  A0 += bat * aBatch;
  if (SPLIT) A1 += bat * aBatch;
  B += bat * bBatch;
  if (!POOL) C += bat * cBatch;
  int tid = threadIdx.x, lane = tid & 63;
  int w = tid >> 6;
  int wm = (w >> 1) * 64, wn = (w & 1) * 64;
  f32x4 acc[4][4];
  #pragma unroll
  for (int i = 0; i < 4; i++)
    #pragma unroll
    for (int j = 0; j < 4; j++) acc[i][j] = (f32x4){0.f, 0.f, 0.f, 0.f};

  int sRow = tid >> 2;
  int sCol = ((tid & 3) ^ ((tid >> 3) & 3)) * 8;        // swizzled source chunk
  int fr = lane & 15;
  int fq = ((lane >> 4) ^ ((fr >> 1) & 3)) * 8;         // swizzled read slot

  auto stageG = [&](int buf, int k0){
    const u16* Ap = A0; int kk = k0;
    if (SPLIT && k0 >= 512){ Ap = A1; kk = k0 - 512; }
    const u16* ga = Ap + (size_t)(m0 + sRow) * 512 + kk + sCol;
    const u16* gb = B  + (size_t)(n0 + sRow) * ldb + k0 + sCol;
    __builtin_amdgcn_global_load_lds(GLOBAL_AS(ga),                    LDS_AS(&As[buf][tid * 8]),        16, 0, 0);
    __builtin_amdgcn_global_load_lds(GLOBAL_AS(ga + (size_t)64 * 512), LDS_AS(&As[buf][2048 + tid * 8]), 16, 0, 0);
    __builtin_amdgcn_global_load_lds(GLOBAL_AS(gb),                    LDS_AS(&Bs[buf][tid * 8]),        16, 0, 0);
    __builtin_amdgcn_global_load_lds(GLOBAL_AS(gb + (size_t)64 * ldb), LDS_AS(&Bs[buf][2048 + tid * 8]), 16, 0, 0);
  };

  stageG(0, 0);

  int nIt = K >> 5;
  for (int it = 0; it < nIt; ++it){
    if (it + 1 < nIt){ stageG((it + 1) & 1, (it + 1) * 32); bar_vm4(); }
    else             { bar_vm0(); }
    bf16x8 af[4], bfr[4];
    #pragma unroll
    for (int i = 0; i < 4; i++) af[i]  = *(const bf16x8*)&As[it & 1][(wm + i * 16 + fr) * 32 + fq];
    #pragma unroll
    for (int j = 0; j < 4; j++) bfr[j] = *(const bf16x8*)&Bs[it & 1][(wn + j * 16 + fr) * 32 + fq];
    #pragma unroll
    for (int i = 0; i < 4; i++)
      #pragma unroll
      for (int j = 0; j < 4; j++)
        acc[i][j] = __builtin_amdgcn_mfma_f32_16x16x32_bf16(af[i], bfr[j], acc[i][j], 0, 0, 0);
    bar_end();
  }

  if constexpr (POOL){
    #pragma unroll
    for (int j = 0; j < 4; j++){
      float p = 0.f;
      #pragma unroll
      for (int i = 0; i < 4; i++)
        #pragma unroll
        for (int r = 0; r < 4; r++) p += acc[i][j][r];
      p += __shfl_xor(p, 16);
      p += __shfl_xor(p, 32);
      if (lane < 16){
        int col = n0 + wn + j * 16 + lane;
        atomicAdd(poolOut + ((size_t)(b0) + bat) * 512 + col, p * (1.0f / 512.0f));
      }
    }
  } else {
    int cq = (lane >> 4) * 4, cc = lane & 15;
    #pragma unroll
    for (int i = 0; i < 4; i++){
      #pragma unroll
      for (int j = 0; j < 4; j++){
        #pragma unroll
        for (int r = 0; r < 4; r++){
          int row = m0 + wm + i * 16 + cq + r;
          int col = n0 + wn + j * 16 + cc;
          float v = acc[i][j][r];
          if (TANH) v = tanhf(v);
          if constexpr (sizeof(CT) == 4) C[(size_t)row * 512 + col] = v;
          else                           C[(size_t)row * 512 + col] = f2b(v);
        }
      }
    }
  }
}

extern "C" void kernel_launch(void* const* d_in, const int* in_sizes, int n_in,
                              void* d_out, int out_size, void* d_ws, size_t ws_size,
                              hipStream_t stream) {
  const float* emb   = (const float*)d_in[0];   // [256,512,512]
  const float* Win1  = (const float*)d_in[1];   // [512,512]
  const float* Wout1 = (const float*)d_in[2];   // [512,1024]
  const float* Win2  = (const float*)d_in[3];
  const float* Wout2 = (const float*)d_in[4];
  float* out = (float*)d_out;                   // [256,512]

  // workspace: 4 MB weights + CB * 5 bf16 buffers (x, q, xT, xNext, mix)
  int CB = 256;
  while (CB > 8 && (4ull << 20) + (size_t)CB * (5ull * 524288ull) > ws_size) CB >>= 1;
  const int64_t E = 262144;

  char* wsb = (char*)d_ws;
  u16* Win1b  = (u16*)wsb;
  u16* Wout1b = Win1b + 262144;
  u16* Win2b  = Wout1b + 524288;
  u16* Wout2b = Win2b + 262144;
  u16* base = (u16*)(wsb + (4 << 20));
  // live ranges: Ar: x1 -> q2 | Br: q1 | Cr: xT1 -> xT2 | Dr: x2 | Fr: mix1 -> mix2
  u16* Ar = base;
  u16* Br = base + (size_t)CB * E;
  u16* Cr = base + 2 * (size_t)CB * E;
  u16* Dr = base + 3 * (size_t)CB * E;
  u16* Fr = base + 4 * (size_t)CB * E;

  hipMemsetAsync(d_out, 0, (size_t)out_size * sizeof(float), stream);

  cvt_bf16_kernel<<<256, 256, 0, stream>>>(Win1,  Win1b,  262144);
  cvt_bf16_kernel<<<512, 256, 0, stream>>>(Wout1, Wout1b, 524288);
  cvt_bf16_kernel<<<256, 256, 0, stream>>>(Win2,  Win2b,  262144);
  cvt_bf16_kernel<<<512, 256, 0, stream>>>(Wout2, Wout2b, 524288);

  dim3 gg(16, CB);        // gemm grid
  dim3 gt(64, CB);        // transpose / cvtT tiles
  int nAttnBlocks = CB * 8;    // QBLK=64 -> 8 q-tiles per batch
  int batPerXcd = CB / 8;

  for (int c = 0; c < 256 / CB; c++){
    const float* embc = emb + (size_t)c * CB * 262144;
    int b0 = c * CB;

    // ---- block 1 (tanh) ----
    cvtT_kernel<<<gt, 256, 0, stream>>>(embc, Ar, Cr);                     // x1 -> Ar, xT1 -> Cr
    gemm_bt_kernel<false,false,false,u16><<<gg, 256, 0, stream>>>(
        Ar, nullptr, Win1b, Br, 512, 512, E, 0, E, nullptr, 0);            // q1 -> Br
    attn_kernel<<<nAttnBlocks, 512, 0, stream>>>(Br, Ar, Cr, Fr, batPerXcd); // mix1 -> Fr
    gemm_bt_kernel<true,true,false,u16><<<gg, 256, 0, stream>>>(
        Fr, Br, Wout1b, Dr, 1024, 1024, E, 0, E, nullptr, 0);              // x2 -> Dr (tanh)

    // ---- block 2 (no tanh) + fused mean-pool ----
    transpose512_kernel<<<gt, 256, 0, stream>>>(Dr, Cr);                   // xT2 -> Cr
    gemm_bt_kernel<false,false,false,u16><<<gg, 256, 0, stream>>>(
        Dr, nullptr, Win2b, Ar, 512, 512, E, 0, E, nullptr, 0);            // q2 -> Ar
    attn_kernel<<<nAttnBlocks, 512, 0, stream>>>(Ar, Dr, Cr, Fr, batPerXcd); // mix2 -> Fr
    gemm_bt_kernel<true,false,true,u16><<<gg, 256, 0, stream>>>(
        Fr, Ar, Wout2b, (u16*)nullptr, 1024, 1024, E, 0, 0, out, b0);      // pooled out
  }
}

// Round 5
// 1631.596 us; speedup vs baseline: 1.2517x; 1.0475x over previous
//
#include <hip/hip_runtime.h>
#include <cstdint>
#include <cstddef>

typedef uint16_t u16;
typedef __attribute__((ext_vector_type(8))) short bf16x8;   // 8 bf16 = 4 VGPRs (guide §3)
typedef __attribute__((ext_vector_type(4))) float f32x4;
typedef __attribute__((ext_vector_type(4))) uint16_t u16x4;

#define GLOBAL_AS(p) (const __attribute__((address_space(1))) void*)(p)
#define LDS_AS(p)    (__attribute__((address_space(3))) void*)(p)

// T4 counted-vmcnt barriers (gemm) + lgkm-only barrier (attn softmax).
__device__ __forceinline__ void bar_vm4(){      // wait until <=4 vmem outstanding
  asm volatile("s_waitcnt vmcnt(4)" ::: "memory");
  __builtin_amdgcn_s_barrier();
  asm volatile("" ::: "memory");
}
__device__ __forceinline__ void bar_vm0(){      // full drain (loop tail only)
  asm volatile("s_waitcnt vmcnt(0)" ::: "memory");
  __builtin_amdgcn_s_barrier();
  asm volatile("" ::: "memory");
}
__device__ __forceinline__ void bar_end(){      // execution-only barrier (reads already consumed)
  asm volatile("" ::: "memory");
  __builtin_amdgcn_s_barrier();
  asm volatile("" ::: "memory");
}
__device__ __forceinline__ void bar_lgkm(){     // LDS-only sync; vmem prefetch stays in flight
  asm volatile("s_waitcnt lgkmcnt(0)" ::: "memory");
  __builtin_amdgcn_s_barrier();
  asm volatile("" ::: "memory");
}

__device__ __forceinline__ u16 f2b(float f){
  uint32_t u = __float_as_uint(f);
  u += 0x7fff + ((u >> 16) & 1);            // RNE
  return (u16)(u >> 16);
}

// ---------------- fp32 -> bf16 convert (vector x4) ----------------
__global__ void cvt_bf16_kernel(const float* __restrict__ src, u16* __restrict__ dst, int n){
  int i = (blockIdx.x * 256 + threadIdx.x) * 4;
  if (i >= n) return;
  float4 f = *(const float4*)(src + i);
  u16x4 o; o.x = f2b(f.x); o.y = f2b(f.y); o.z = f2b(f.z); o.w = f2b(f.w);
  *(u16x4*)(dst + i) = o;
}

// ------- fused fp32->bf16 convert + copy + transpose (block-1 input path) -------
__global__ void cvtT_kernel(const float* __restrict__ src, u16* __restrict__ x, u16* __restrict__ xT){
  __shared__ u16 tile[64][68];
  size_t b = blockIdx.y;
  int t = blockIdx.x;
  int r0 = (t >> 3) * 64, c0 = (t & 7) * 64;
  const float* s = src + b * 262144;
  u16* dx = x + b * 262144;
  u16* dT = xT + b * 262144;
  int tx = threadIdx.x & 63, ty = threadIdx.x >> 6;
  #pragma unroll
  for (int k = 0; k < 16; k++){
    int r = ty * 16 + k;
    u16 v = f2b(s[(size_t)(r0 + r) * 512 + c0 + tx]);
    dx[(size_t)(r0 + r) * 512 + c0 + tx] = v;
    tile[r][tx] = v;
  }
  __syncthreads();
  #pragma unroll
  for (int k = 0; k < 16; k++){
    int c = ty * 16 + k;
    dT[(size_t)(c0 + c) * 512 + r0 + tx] = tile[tx][c];
  }
}

// ---------------- 512x512 bf16 transpose (batched, 64x64 tiles) ----------------
__global__ void transpose512_kernel(const u16* __restrict__ src, u16* __restrict__ dst){
  __shared__ u16 tile[64][68];
  size_t b = blockIdx.y;
  int t = blockIdx.x;
  int r0 = (t >> 3) * 64, c0 = (t & 7) * 64;
  const u16* s = src + b * 262144;
  u16* d = dst + b * 262144;
  int tx = threadIdx.x & 63, ty = threadIdx.x >> 6;
  #pragma unroll
  for (int k = 0; k < 16; k++){
    int r = ty * 16 + k;
    tile[r][tx] = s[(size_t)(r0 + r) * 512 + c0 + tx];
  }
  __syncthreads();
  #pragma unroll
  for (int k = 0; k < 16; k++){
    int c = ty * 16 + k;
    d[(size_t)(c0 + c) * 512 + r0 + tx] = tile[tx][c];
  }
}

// ======== fused attention: S = q@x^T, P = softmax(S), mix = P@x  (per batch) ========
// v5: PER-WAVE decoupled staging. Wave w only ever consumes B-rows [w*64, w*64+64),
// so each wave stages its own 4 KB sub-tile into its own Bx region and waits on its
// own counted vmcnt -- ZERO barriers in both k-loops. The 8 waves (2/SIMD) stall
// independently (m114 wave-overlap), replacing the R4 lockstep convoy.
// Per iter: vmcnt(4) [own tile landed, next in flight] -> ds_read -> lgkmcnt(0)
// [LDS slot free] -> stage tile it+2 into just-freed buffer -> MFMA.
// Chunk swizzle (rule m173/21): source chunk pre-XORed, read slot XORed identically.
__global__ __launch_bounds__(512, 2) void attn_kernel(
    const u16* __restrict__ q, const u16* __restrict__ x, const u16* __restrict__ xT,
    u16* __restrict__ mix, int batPerXcd)
{
  __shared__ __align__(16) u16 U[64 * 520];        // 66.6 KB: q-tile, then P (bf16)
  __shared__ __align__(16) u16 Bx[2][8][64 * 32];  // [buf][wave][4 KB] = 64 KB
  __shared__ float stats[2][64][8];                // row max / row sum partials per wave
  const int64_t E = 262144;
  int id = blockIdx.x;
  int tile = (id >> 3) & 7;
  int64_t bat = (int64_t)(id & 7) * batPerXcd + (id >> 6);
  q += bat * E; x += bat * E; xT += bat * E; mix += bat * E;
  int m0 = tile * 64;
  int tid = threadIdx.x, lane = tid & 63, w = tid >> 6;
  int fr = lane & 15, qd = lane >> 4;
  int fq = qd * 8;                                 // U chunk (pitch 520 spreads banks)
  int bslot = (qd ^ ((fr >> 1) & 3)) * 8;          // swizzled read slot for Bx

  // per-wave stage: 4 instrs, each writes 16 rows (64 lanes x 16B) of this wave's region.
  // lane covers row_local = s*16 + (lane>>2), stored chunk-slot = lane&3;
  // source chunk = slot ^ ((row_local>>1)&3) so read-side XOR recovers chunk qd.
  auto stage = [&](const u16* __restrict__ src, int buf, int k0){
    #pragma unroll
    for (int s = 0; s < 4; s++){
      int rloc = s * 16 + (lane >> 2);
      int chunk = (lane & 3) ^ ((rloc >> 1) & 3);
      const u16* g = src + (size_t)(w * 64 + rloc) * 512 + k0 + chunk * 8;
      __builtin_amdgcn_global_load_lds(GLOBAL_AS(g), LDS_AS(&Bx[buf][w][s * 512 + lane * 8]), 16, 0, 0);
    }
  };

  // q-tile first (so vmcnt(8) drains it while x tiles stay in flight):
  // [64x512] -> U pitch 520; wave w, chunk c stages full row c*8+w.
  #pragma unroll
  for (int c = 0; c < 8; c++){
    int row = c * 8 + w;
    __builtin_amdgcn_global_load_lds(GLOBAL_AS(q + (size_t)(m0 + row) * 512 + lane * 8),
                                     LDS_AS(&U[row * 520 + lane * 8]), 16, 0, 0);
  }
  stage(x, 0, 0);                                  // tile0 -> buf0 (4 loads)
  stage(x, 1, 32);                                 // tile1 -> buf1 (4 loads)
  asm volatile("s_waitcnt vmcnt(8)" ::: "memory"); // q landed; x0,x1 in flight
  __builtin_amdgcn_s_barrier();                    // U(q) visible to all waves
  asm volatile("" ::: "memory");

  f32x4 acc[4][4];
  #pragma unroll
  for (int i = 0; i < 4; i++)
    #pragma unroll
    for (int j = 0; j < 4; j++) acc[i][j] = (f32x4){0.f, 0.f, 0.f, 0.f};

  // ---- phase 1: S = q @ x^T  (barrier-free; per-wave pipeline) ----
  #pragma unroll
  for (int it = 0; it < 16; ++it){
    asm volatile("s_waitcnt vmcnt(4)" ::: "memory");   // own tile `it` landed
    int k0 = it * 32;
    bf16x8 af[4], bfr[4];
    #pragma unroll
    for (int i = 0; i < 4; i++) af[i]  = *(const bf16x8*)&U[(i * 16 + fr) * 520 + k0 + fq];
    #pragma unroll
    for (int j = 0; j < 4; j++) bfr[j] = *(const bf16x8*)&Bx[it & 1][w][(j * 16 + fr) * 32 + bslot];
    asm volatile("s_waitcnt lgkmcnt(0)" ::: "memory"); // reads in regs; buffer free
    if (it <= 13)      stage(x,  it & 1, (it + 2) * 32);
    else if (it == 14) stage(xT, 0, 0);                // phase-3 tile0
    else               stage(xT, 1, 32);               // phase-3 tile1
    #pragma unroll
    for (int i = 0; i < 4; i++)
      #pragma unroll
      for (int j = 0; j < 4; j++)
        acc[i][j] = __builtin_amdgcn_mfma_f32_16x16x32_bf16(af[i], bfr[j], acc[i][j], 0, 0, 0);
  }

  // ---- phase 2: softmax over full 512 keys (xT tile0/1 in flight throughout) ----
  // S C-layout: row(l) = i*16 + qd*4 + r, col(key) = w*64 + j*16 + fr
  float inv[4][4];
  #pragma unroll
  for (int i = 0; i < 4; i++)
    #pragma unroll
    for (int r = 0; r < 4; r++){
      float m = acc[i][0][r];
      #pragma unroll
      for (int j = 1; j < 4; j++) m = fmaxf(m, acc[i][j][r]);
      #pragma unroll
      for (int o = 1; o <= 8; o <<= 1) m = fmaxf(m, __shfl_xor(m, o));
      if (fr == 0) stats[0][i * 16 + qd * 4 + r][w] = m;
    }
  bar_lgkm();
  #pragma unroll
  for (int i = 0; i < 4; i++)
    #pragma unroll
    for (int r = 0; r < 4; r++){
      int row = i * 16 + qd * 4 + r;
      float m = stats[0][row][0];
      #pragma unroll
      for (int t = 1; t < 8; t++) m = fmaxf(m, stats[0][row][t]);
      float s = 0.f;
      #pragma unroll
      for (int j = 0; j < 4; j++){
        float e = __expf(acc[i][j][r] - m);
        acc[i][j][r] = e; s += e;
      }
      #pragma unroll
      for (int o = 1; o <= 8; o <<= 1) s += __shfl_xor(s, o);
      if (fr == 0) stats[1][row][w] = s;
    }
  bar_lgkm();
  #pragma unroll
  for (int i = 0; i < 4; i++)
    #pragma unroll
    for (int r = 0; r < 4; r++){
      int row = i * 16 + qd * 4 + r;
      float s = stats[1][row][0];
      #pragma unroll
      for (int t = 1; t < 8; t++) s += stats[1][row][t];
      inv[i][r] = 1.0f / s;
    }
  // P (bf16) -> U, pair-packed b32 (even lane writes its + neighbor's col)
  #pragma unroll
  for (int i = 0; i < 4; i++)
    #pragma unroll
    for (int r = 0; r < 4; r++)
      #pragma unroll
      for (int j = 0; j < 4; j++){
        int row = i * 16 + qd * 4 + r;
        int col = w * 64 + j * 16 + fr;
        uint32_t mine = f2b(acc[i][j][r] * inv[i][r]);
        uint32_t oth = (uint32_t)__shfl_xor((int)mine, 1);
        if (!(fr & 1)) *(uint32_t*)&U[row * 520 + col] = mine | (oth << 16);
      }
  bar_lgkm();         // P visible to all waves; xT tiles still in flight (vmcnt untouched)

  // ---- phase 3: mix = P @ x  (barrier-free; per-wave pipeline on xT) ----
  #pragma unroll
  for (int i = 0; i < 4; i++)
    #pragma unroll
    for (int j = 0; j < 4; j++) acc[i][j] = (f32x4){0.f, 0.f, 0.f, 0.f};
  #pragma unroll
  for (int it = 0; it < 16; ++it){
    if (it < 15) asm volatile("s_waitcnt vmcnt(4)" ::: "memory");
    else         asm volatile("s_waitcnt vmcnt(0)" ::: "memory");
    int k0 = it * 32;
    bf16x8 af[4], bfr[4];
    #pragma unroll
    for (int i = 0; i < 4; i++) af[i]  = *(const bf16x8*)&U[(i * 16 + fr) * 520 + k0 + fq];
    #pragma unroll
    for (int j = 0; j < 4; j++) bfr[j] = *(const bf16x8*)&Bx[it & 1][w][(j * 16 + fr) * 32 + bslot];
    asm volatile("s_waitcnt lgkmcnt(0)" ::: "memory");
    if (it <= 13) stage(xT, it & 1, (it + 2) * 32);
    #pragma unroll
    for (int i = 0; i < 4; i++)
      #pragma unroll
      for (int j = 0; j < 4; j++)
        acc[i][j] = __builtin_amdgcn_mfma_f32_16x16x32_bf16(af[i], bfr[j], acc[i][j], 0, 0, 0);
  }
  // epilogue: mix bf16, C-layout
  #pragma unroll
  for (int i = 0; i < 4; i++)
    #pragma unroll
    for (int j = 0; j < 4; j++)
      #pragma unroll
      for (int r = 0; r < 4; r++)
        mix[(size_t)(m0 + i * 16 + qd * 4 + r) * 512 + w * 64 + j * 16 + fr] =
            f2b(acc[i][j][r]);
}

// ---------------- bf16 MFMA GEMM: C[512,512] = A[512,K] @ B[512,K]^T (batched) ----------------
// XCD swizzle: m0 = bx&3 so same-XCD blocks (bx, bx+8) share the A m-tile (L2 reuse).
// T4 counted-vmcnt pipeline + chunk swizzle (unchanged from R4).
template<bool SPLIT, bool TANH, bool POOL, typename CT>
__global__ __launch_bounds__(256, 2) void gemm_bt_kernel(
    const u16* __restrict__ A0, const u16* __restrict__ A1,
    const u16* __restrict__ B, CT* __restrict__ C,
    int K, int ldb, int64_t aBatch, int64_t bBatch, int64_t cBatch,
    float* __restrict__ poolOut, int b0)
{
  __shared__ __align__(16) u16 As[2][128 * 32];
  __shared__ __align__(16) u16 Bs[2][128 * 32];
  int64_t bat = blockIdx.y;
  int m0 = (blockIdx.x & 3) * 128, n0 = (blockIdx.x >> 2) * 128;
  A0 += bat * aBatch;
  if (SPLIT) A1 += bat * aBatch;
  B += bat * bBatch;
  if (!POOL) C += bat * cBatch;
  int tid = threadIdx.x, lane = tid & 63;
  int w = tid >> 6;
  int wm = (w >> 1) * 64, wn = (w & 1) * 64;
  f32x4 acc[4][4];
  #pragma unroll
  for (int i = 0; i < 4; i++)
    #pragma unroll
    for (int j = 0; j < 4; j++) acc[i][j] = (f32x4){0.f, 0.f, 0.f, 0.f};

  int sRow = tid >> 2;
  int sCol = ((tid & 3) ^ ((tid >> 3) & 3)) * 8;        // swizzled source chunk
  int fr = lane & 15;
  int fq = ((lane >> 4) ^ ((fr >> 1) & 3)) * 8;         // swizzled read slot

  auto stageG = [&](int buf, int k0){
    const u16* Ap = A0; int kk = k0;
    if (SPLIT && k0 >= 512){ Ap = A1; kk = k0 - 512; }
    const u16* ga = Ap + (size_t)(m0 + sRow) * 512 + kk + sCol;
    const u16* gb = B  + (size_t)(n0 + sRow) * ldb + k0 + sCol;
    __builtin_amdgcn_global_load_lds(GLOBAL_AS(ga),                    LDS_AS(&As[buf][tid * 8]),        16, 0, 0);
    __builtin_amdgcn_global_load_lds(GLOBAL_AS(ga + (size_t)64 * 512), LDS_AS(&As[buf][2048 + tid * 8]), 16, 0, 0);
    __builtin_amdgcn_global_load_lds(GLOBAL_AS(gb),                    LDS_AS(&Bs[buf][tid * 8]),        16, 0, 0);
    __builtin_amdgcn_global_load_lds(GLOBAL_AS(gb + (size_t)64 * ldb), LDS_AS(&Bs[buf][2048 + tid * 8]), 16, 0, 0);
  };

  stageG(0, 0);

  int nIt = K >> 5;
  for (int it = 0; it < nIt; ++it){
    if (it + 1 < nIt){ stageG((it + 1) & 1, (it + 1) * 32); bar_vm4(); }
    else             { bar_vm0(); }
    bf16x8 af[4], bfr[4];
    #pragma unroll
    for (int i = 0; i < 4; i++) af[i]  = *(const bf16x8*)&As[it & 1][(wm + i * 16 + fr) * 32 + fq];
    #pragma unroll
    for (int j = 0; j < 4; j++) bfr[j] = *(const bf16x8*)&Bs[it & 1][(wn + j * 16 + fr) * 32 + fq];
    #pragma unroll
    for (int i = 0; i < 4; i++)
      #pragma unroll
      for (int j = 0; j < 4; j++)
        acc[i][j] = __builtin_amdgcn_mfma_f32_16x16x32_bf16(af[i], bfr[j], acc[i][j], 0, 0, 0);
    bar_end();
  }

  if constexpr (POOL){
    #pragma unroll
    for (int j = 0; j < 4; j++){
      float p = 0.f;
      #pragma unroll
      for (int i = 0; i < 4; i++)
        #pragma unroll
        for (int r = 0; r < 4; r++) p += acc[i][j][r];
      p += __shfl_xor(p, 16);
      p += __shfl_xor(p, 32);
      if (lane < 16){
        int col = n0 + wn + j * 16 + lane;
        atomicAdd(poolOut + ((size_t)(b0) + bat) * 512 + col, p * (1.0f / 512.0f));
      }
    }
  } else {
    int cq = (lane >> 4) * 4, cc = lane & 15;
    #pragma unroll
    for (int i = 0; i < 4; i++){
      #pragma unroll
      for (int j = 0; j < 4; j++){
        #pragma unroll
        for (int r = 0; r < 4; r++){
          int row = m0 + wm + i * 16 + cq + r;
          int col = n0 + wn + j * 16 + cc;
          float v = acc[i][j][r];
          if (TANH) v = tanhf(v);
          if constexpr (sizeof(CT) == 4) C[(size_t)row * 512 + col] = v;
          else                           C[(size_t)row * 512 + col] = f2b(v);
        }
      }
    }
  }
}

extern "C" void kernel_launch(void* const* d_in, const int* in_sizes, int n_in,
                              void* d_out, int out_size, void* d_ws, size_t ws_size,
                              hipStream_t stream) {
  const float* emb   = (const float*)d_in[0];   // [256,512,512]
  const float* Win1  = (const float*)d_in[1];   // [512,512]
  const float* Wout1 = (const float*)d_in[2];   // [512,1024]
  const float* Win2  = (const float*)d_in[3];
  const float* Wout2 = (const float*)d_in[4];
  float* out = (float*)d_out;                   // [256,512]

  // workspace: 4 MB weights + CB * 5 bf16 buffers (x, q, xT, xNext, mix)
  int CB = 256;
  while (CB > 8 && (4ull << 20) + (size_t)CB * (5ull * 524288ull) > ws_size) CB >>= 1;
  const int64_t E = 262144;

  char* wsb = (char*)d_ws;
  u16* Win1b  = (u16*)wsb;
  u16* Wout1b = Win1b + 262144;
  u16* Win2b  = Wout1b + 524288;
  u16* Wout2b = Win2b + 262144;
  u16* base = (u16*)(wsb + (4 << 20));
  // live ranges: Ar: x1 -> q2 | Br: q1 | Cr: xT1 -> xT2 | Dr: x2 | Fr: mix1 -> mix2
  u16* Ar = base;
  u16* Br = base + (size_t)CB * E;
  u16* Cr = base + 2 * (size_t)CB * E;
  u16* Dr = base + 3 * (size_t)CB * E;
  u16* Fr = base + 4 * (size_t)CB * E;

  hipMemsetAsync(d_out, 0, (size_t)out_size * sizeof(float), stream);

  cvt_bf16_kernel<<<256, 256, 0, stream>>>(Win1,  Win1b,  262144);
  cvt_bf16_kernel<<<512, 256, 0, stream>>>(Wout1, Wout1b, 524288);
  cvt_bf16_kernel<<<256, 256, 0, stream>>>(Win2,  Win2b,  262144);
  cvt_bf16_kernel<<<512, 256, 0, stream>>>(Wout2, Wout2b, 524288);

  dim3 gg(16, CB);        // gemm grid
  dim3 gt(64, CB);        // transpose / cvtT tiles
  int nAttnBlocks = CB * 8;    // QBLK=64 -> 8 q-tiles per batch
  int batPerXcd = CB / 8;

  for (int c = 0; c < 256 / CB; c++){
    const float* embc = emb + (size_t)c * CB * 262144;
    int b0 = c * CB;

    // ---- block 1 (tanh) ----
    cvtT_kernel<<<gt, 256, 0, stream>>>(embc, Ar, Cr);                     // x1 -> Ar, xT1 -> Cr
    gemm_bt_kernel<false,false,false,u16><<<gg, 256, 0, stream>>>(
        Ar, nullptr, Win1b, Br, 512, 512, E, 0, E, nullptr, 0);            // q1 -> Br
    attn_kernel<<<nAttnBlocks, 512, 0, stream>>>(Br, Ar, Cr, Fr, batPerXcd); // mix1 -> Fr
    gemm_bt_kernel<true,true,false,u16><<<gg, 256, 0, stream>>>(
        Fr, Br, Wout1b, Dr, 1024, 1024, E, 0, E, nullptr, 0);              // x2 -> Dr (tanh)

    // ---- block 2 (no tanh) + fused mean-pool ----
    transpose512_kernel<<<gt, 256, 0, stream>>>(Dr, Cr);                   // xT2 -> Cr
    gemm_bt_kernel<false,false,false,u16><<<gg, 256, 0, stream>>>(
        Dr, nullptr, Win2b, Ar, 512, 512, E, 0, E, nullptr, 0);            // q2 -> Ar
    attn_kernel<<<nAttnBlocks, 512, 0, stream>>>(Ar, Dr, Cr, Fr, batPerXcd); // mix2 -> Fr
    gemm_bt_kernel<true,false,true,u16><<<gg, 256, 0, stream>>>(
        Fr, Ar, Wout2b, (u16*)nullptr, 1024, 1024, E, 0, 0, out, b0);      // pooled out
  }
}